// Round 4
// baseline (117.379 us; speedup 1.0000x reference)
//
#include <hip/hip_runtime.h>
#include <math.h>

#define Bn 256
#define Nn 1024
#define Dn 128
#define Hn 8
#define HDn 16
#define NEG_INF -1.0e15f

// ---------------- K0: Q = h_c @ Wq.T + bq ----------------
__global__ __launch_bounds__(128) void k_q(
    const float* __restrict__ h_g, const float* __restrict__ first,
    const float* __restrict__ last, const float* __restrict__ context,
    const float* __restrict__ Wq, const float* __restrict__ bq,
    float* __restrict__ Qout)
{
    __shared__ __align__(16) float hc[3 * Dn + 2];
    const int b = blockIdx.x;
    const int t = threadIdx.x;
    hc[t]          = h_g[b * Dn + t];
    hc[Dn + t]     = first[b * Dn + t];
    hc[2 * Dn + t] = last[b * Dn + t];
    if (t < 2) hc[3 * Dn + t] = context[b * 2 + t];
    __syncthreads();

    const float2* w2 = (const float2*)(Wq + (size_t)t * (3 * Dn + 2));
    const float2* h2 = (const float2*)hc;
    float acc = bq[t];
#pragma unroll 8
    for (int k = 0; k < (3 * Dn + 2) / 2; ++k) {
        float2 w = w2[k], h = h2[k];
        acc = fmaf(w.x, h.x, fmaf(w.y, h.y, acc));
    }
    Qout[b * Dn + t] = acc;
}

// ---------------- K1: single-pass attention, whole-key threads ----------------
// Block = (b, head-pair-half): 512 blocks x 512 threads. Thread owns 8 whole
// keys of one head; no cross-lane ops in the hot loop; depth-2 key pipeline.
// Softmax without max-subtraction (scores ~N(0,1); exp-safe; shift-invariant).
__global__ __launch_bounds__(512, 4) void k_attn(
    const float* __restrict__ Q, const float* __restrict__ K,
    const float* __restrict__ V, const int* __restrict__ mask,
    float* __restrict__ Uout)
{
    __shared__ float sQ[64];
    __shared__ float sPart[512][17];   // [tid][0..15]=u partial, [16]=sum partial
    __shared__ float sOut[64];
    __shared__ float sSum[4];

    const int blk = blockIdx.x;
    const int b = blk >> 1, pr = blk & 1;      // head half: heads pr*4 .. pr*4+3
    const int tid = threadIdx.x;
    const int hl = tid >> 7;                    // local head 0..3
    const int h = pr * 4 + hl;
    const int lh = tid & 127;                   // lane within head

    if (tid < 64) sQ[tid] = Q[b * Dn + pr * 64 + tid];

    const int* __restrict__ mrow = mask + (size_t)b * Nn;
    int mk[8];
#pragma unroll
    for (int i = 0; i < 8; ++i) mk[i] = mrow[lh + 128 * i];

    __syncthreads();
    float4 q4[4];
#pragma unroll
    for (int j = 0; j < 4; ++j) q4[j] = ((const float4*)(sQ + hl * 16))[j];

    const float4* __restrict__ Kp = (const float4*)(K + ((size_t)b * Hn + h) * Nn * HDn);
    const float4* __restrict__ Vp = (const float4*)(V + ((size_t)b * Hn + h) * Nn * HDn);

    float4 kb[2][4], vb[2][4];
#pragma unroll
    for (int j = 0; j < 4; ++j) {
        kb[0][j] = Kp[(size_t)lh * 4 + j];
        vb[0][j] = Vp[(size_t)lh * 4 + j];
    }

    float4 u0 = {0,0,0,0}, u1 = {0,0,0,0}, u2 = {0,0,0,0}, u3 = {0,0,0,0};
    float sum = 0.f;

#pragma unroll
    for (int i = 0; i < 8; ++i) {
        const int cur = i & 1, nxt = cur ^ 1;
        if (i < 7) {
            const int n = lh + 128 * (i + 1);
#pragma unroll
            for (int j = 0; j < 4; ++j) {
                kb[nxt][j] = Kp[(size_t)n * 4 + j];
                vb[nxt][j] = Vp[(size_t)n * 4 + j];
            }
        }
        __builtin_amdgcn_sched_barrier(0);   // keep prefetch above compute
        float s = 0.f;
#pragma unroll
        for (int j = 0; j < 4; ++j) {
            s = fmaf(q4[j].x, kb[cur][j].x, s);
            s = fmaf(q4[j].y, kb[cur][j].y, s);
            s = fmaf(q4[j].z, kb[cur][j].z, s);
            s = fmaf(q4[j].w, kb[cur][j].w, s);
        }
        const float e = mk[i] ? __expf(s * 0.25f) : 0.f;   // /sqrt(16)
        sum += e;
        u0.x = fmaf(e, vb[cur][0].x, u0.x); u0.y = fmaf(e, vb[cur][0].y, u0.y);
        u0.z = fmaf(e, vb[cur][0].z, u0.z); u0.w = fmaf(e, vb[cur][0].w, u0.w);
        u1.x = fmaf(e, vb[cur][1].x, u1.x); u1.y = fmaf(e, vb[cur][1].y, u1.y);
        u1.z = fmaf(e, vb[cur][1].z, u1.z); u1.w = fmaf(e, vb[cur][1].w, u1.w);
        u2.x = fmaf(e, vb[cur][2].x, u2.x); u2.y = fmaf(e, vb[cur][2].y, u2.y);
        u2.z = fmaf(e, vb[cur][2].z, u2.z); u2.w = fmaf(e, vb[cur][2].w, u2.w);
        u3.x = fmaf(e, vb[cur][3].x, u3.x); u3.y = fmaf(e, vb[cur][3].y, u3.y);
        u3.z = fmaf(e, vb[cur][3].z, u3.z); u3.w = fmaf(e, vb[cur][3].w, u3.w);
    }

    // write partials
    {
        float* p = sPart[tid];
        p[0]=u0.x; p[1]=u0.y; p[2]=u0.z; p[3]=u0.w;
        p[4]=u1.x; p[5]=u1.y; p[6]=u1.z; p[7]=u1.w;
        p[8]=u2.x; p[9]=u2.y; p[10]=u2.z; p[11]=u2.w;
        p[12]=u3.x; p[13]=u3.y; p[14]=u3.z; p[15]=u3.w;
        p[16]=sum;
    }
    __syncthreads();

    if (tid < 64) {
        const int hh = tid >> 4, d = tid & 15;
        float a = 0.f;
#pragma unroll 8
        for (int j = 0; j < 128; ++j) a += sPart[hh * 128 + j][d];
        sOut[tid] = a;
    } else if (tid < 68) {
        const int hh = tid - 64;
        float a = 0.f;
#pragma unroll 8
        for (int j = 0; j < 128; ++j) a += sPart[hh * 128 + j][16];
        sSum[hh] = a;
    }
    __syncthreads();
    if (tid < 64) {
        Uout[b * Dn + pr * 64 + tid] = sOut[tid] / sSum[tid >> 4];
    }
}

// ---------------- K2: u2 = u@Wo.T + bo; pointer logits; softmax; argmax ----------------
__global__ __launch_bounds__(1024) void k_ptr(
    const float* __restrict__ U, const float* __restrict__ Wo,
    const float* __restrict__ bo, const float* __restrict__ K_lg,
    const int* __restrict__ mask, float* __restrict__ out)
{
    __shared__ __align__(16) float sU[Dn];
    __shared__ __align__(16) float sU2[Dn];
    __shared__ __align__(16) float sL[Nn];
    __shared__ float sRv[16];
    __shared__ int   sRi[16];
    __shared__ float sRs[16];

    const int b = blockIdx.x;
    const int tid = threadIdx.x;
    const int lane = tid & 63, wave = tid >> 6;

    if (tid < Dn) sU[tid] = U[b * Dn + tid];
    __syncthreads();
    // u2: 8 threads per output dim (1024 thr / 128 dims)
    {
        const int d = tid >> 3, e8 = tid & 7;
        const float4* wrow = (const float4*)(Wo + (size_t)d * Dn + e8 * 16);
        const float4* su4 = (const float4*)(sU + e8 * 16);
        float acc = 0.f;
#pragma unroll
        for (int k = 0; k < 4; ++k) {
            const float4 w = wrow[k], u = su4[k];
            acc = fmaf(w.x, u.x, fmaf(w.y, u.y, fmaf(w.z, u.z, fmaf(w.w, u.w, acc))));
        }
        acc += __shfl_xor(acc, 1, 64);
        acc += __shfl_xor(acc, 2, 64);
        acc += __shfl_xor(acc, 4, 64);
        if (e8 == 0) sU2[d] = acc + bo[d];
    }
    __syncthreads();

    // logits: 32 groups of 32 lanes; 4-deep batched loads
    const float4* __restrict__ Kl = (const float4*)(K_lg + (size_t)b * Nn * Dn);
    const int* __restrict__ mrow = mask + (size_t)b * Nn;
    const int grp = tid >> 5, l32 = tid & 31;
    const float4 u2f = ((const float4*)sU2)[l32];
    const float sc = 0.08838834764831845f;   // 1/sqrt(128)
#pragma unroll
    for (int it0 = 0; it0 < 32; it0 += 4) {
        float4 kl[4];
#pragma unroll
        for (int j = 0; j < 4; ++j)
            kl[j] = Kl[(size_t)(grp + 32 * (it0 + j)) * 32 + l32];
        __builtin_amdgcn_sched_barrier(0);
#pragma unroll
        for (int j = 0; j < 4; ++j) {
            float p = kl[j].x * u2f.x + kl[j].y * u2f.y + kl[j].z * u2f.z + kl[j].w * u2f.w;
#pragma unroll
            for (int o = 16; o >= 1; o >>= 1) p += __shfl_xor(p, o, 64);
            if (l32 == 0) {
                const int n = grp + 32 * (it0 + j);
                sL[n] = (mrow[n] == 0) ? NEG_INF : 10.0f * tanhf(p * sc);
            }
        }
    }
    __syncthreads();

    // block argmax (first-occurrence tie-break) — one key per thread
    float bv = sL[tid]; int bi = tid;
#pragma unroll
    for (int o = 32; o >= 1; o >>= 1) {
        const float ov = __shfl_xor(bv, o, 64);
        const int oi = __shfl_xor(bi, o, 64);
        if (ov > bv || (ov == bv && oi < bi)) { bv = ov; bi = oi; }
    }
    if (lane == 0) { sRv[wave] = bv; sRi[wave] = bi; }
    __syncthreads();
    bv = sRv[0]; bi = sRi[0];
#pragma unroll
    for (int w = 1; w < 16; ++w) {
        const float ov = sRv[w]; const int oi = sRi[w];
        if (ov > bv || (ov == bv && oi < bi)) { bv = ov; bi = oi; }
    }

    // sum of exp(l - max); prob at argmax = 1/sum
    float lsum = __expf(sL[tid] - bv);
#pragma unroll
    for (int o = 32; o >= 1; o >>= 1) lsum += __shfl_xor(lsum, o, 64);
    if (lane == 0) sRs[wave] = lsum;
    __syncthreads();
    if (tid == 0) {
        float tot = 0.f;
#pragma unroll
        for (int w = 0; w < 16; ++w) tot += sRs[w];
        out[b] = (float)bi;            // vertexes (as float32 values)
        out[Bn + b] = 1.0f / tot;      // probs
    }
}

extern "C" void kernel_launch(void* const* d_in, const int* in_sizes, int n_in,
                              void* d_out, int out_size, void* d_ws, size_t ws_size,
                              hipStream_t stream) {
    // inputs: x, h_g, first, last, context, K, V, K_lg, Wq, bq, Wo, bo, mask, t
    const float* h_g     = (const float*)d_in[1];
    const float* first   = (const float*)d_in[2];
    const float* last    = (const float*)d_in[3];
    const float* context = (const float*)d_in[4];
    const float* K       = (const float*)d_in[5];
    const float* V       = (const float*)d_in[6];
    const float* K_lg    = (const float*)d_in[7];
    const float* Wq      = (const float*)d_in[8];
    const float* bq      = (const float*)d_in[9];
    const float* Wo      = (const float*)d_in[10];
    const float* bo      = (const float*)d_in[11];
    const int*   mask    = (const int*)d_in[12];
    float* out = (float*)d_out;

    float* Qws = (float*)d_ws;             // B*D floats
    float* Uws = Qws + Bn * Dn;            // B*D floats

    k_q   <<<Bn,      128, 0, stream>>>(h_g, first, last, context, Wq, bq, Qws);
    k_attn<<<Bn * 2,  512, 0, stream>>>(Qws, K, V, mask, Uws);
    k_ptr <<<Bn,     1024, 0, stream>>>(Uws, Wo, bo, K_lg, mask, out);
}